// Round 7
// baseline (237.276 us; speedup 1.0000x reference)
//
#include <hip/hip_runtime.h>
#include <math.h>

// Match numpy's separate mul/add roundings — no implicit FMA contraction.
// (Explicit __builtin_fmaf below is intentional and unaffected.)
#pragma clang fp contract(off)

#define TPB 256
#define ROWLEN 1024
#define BLOCKS 1024   // 4 waves/block -> 4096 row-streams, 8 rows each

typedef float f32x4 __attribute__((ext_vector_type(4)));

// Uniform-value SGPR hoist (value identical across lanes by construction).
static __device__ __forceinline__ float bcast_f32(float v) {
    return __int_as_float(__builtin_amdgcn_readfirstlane(__float_as_int(v)));
}

// ---- DPP wave64 reductions (VALU-only; no LDS pipe, no barriers) ----
__device__ __forceinline__ float wave_max_dpp(float m) {
    const int NI = 0xff800000;                  // -inf bits (fmax identity)
    int v;
    v = __builtin_amdgcn_update_dpp(NI, __float_as_int(m), 0x111, 0xf, 0xf, false);
    m = fmaxf(m, __int_as_float(v));
    v = __builtin_amdgcn_update_dpp(NI, __float_as_int(m), 0x112, 0xf, 0xf, false);
    m = fmaxf(m, __int_as_float(v));
    v = __builtin_amdgcn_update_dpp(NI, __float_as_int(m), 0x114, 0xf, 0xf, false);
    m = fmaxf(m, __int_as_float(v));
    v = __builtin_amdgcn_update_dpp(NI, __float_as_int(m), 0x118, 0xf, 0xf, false);
    m = fmaxf(m, __int_as_float(v));
    v = __builtin_amdgcn_update_dpp(NI, __float_as_int(m), 0x142, 0xa, 0xf, false);
    m = fmaxf(m, __int_as_float(v));
    v = __builtin_amdgcn_update_dpp(NI, __float_as_int(m), 0x143, 0xc, 0xf, false);
    m = fmaxf(m, __int_as_float(v));
    return __int_as_float(__builtin_amdgcn_readlane(__float_as_int(m), 63));
}

// lo16/hi16 sum chains interleaved (2 independent chains under one latency).
__device__ __forceinline__ void wave_sum_dpp2(unsigned& a, unsigned& b) {
    int v0, v1;
#define SSTG(sel, rm, bm) \
    v0 = __builtin_amdgcn_update_dpp(0, (int)a, sel, rm, bm, false); \
    v1 = __builtin_amdgcn_update_dpp(0, (int)b, sel, rm, bm, false); \
    a += (unsigned)v0; b += (unsigned)v1;
    SSTG(0x111,0xf,0xf) SSTG(0x112,0xf,0xf) SSTG(0x114,0xf,0xf)
    SSTG(0x118,0xf,0xf) SSTG(0x142,0xa,0xf) SSTG(0x143,0xc,0xf)
#undef SSTG
    a = (unsigned)__builtin_amdgcn_readlane((int)a, 63);
    b = (unsigned)__builtin_amdgcn_readlane((int)b, 63);
}

// Exact floor(2^32 / s) without the software f64 division.
// s is an exact integer in [3.6e7, 3.8e10] held exactly in f64; the true
// quotient is <= 117. f32 rcp gives a candidate within 3e-5 absolute of
// the true quotient, so floor() is within +-1 of exact; one exact
// f64-product compare fixes it (qf*s < 2^43: exact). Bit-identical to
// floor(2^32/s).
__device__ __forceinline__ float fac_exact(double s) {
    const float r0 = __builtin_amdgcn_rcpf((float)s);
    float qf = floorf(4294967296.0f * r0);
    const double t = (double)qf * s;               // exact
    if (t > 4294967296.0)           qf -= 1.0f;    // candidate one too high
    else if (t + s <= 4294967296.0) qf += 1.0f;    // candidate one too low
    return qf;
}

// WAVE-per-ROW with wave-private LDS DMA pipeline, zero barriers.
//
// R6 post-mortem: six structural variants all pin at 76-86us, VALUBusy
// 35-49%, BW 2.5 TB/s. The harness fill saturates HBM (6.7 TB/s) at 9.6%
// occupancy / 5% VALU because its waves keep deep store queues in flight
// continuously. Our waves' memory duty cycle is ~3%: 4 loads in flight
// ~900cy, then thousands of compute cycles with ZERO outstanding
// requests (Little's law: 2.5 TB/s needs ~940KB chip-wide in flight; our
// structure supplies ~0.6MB — matches). Register-prefetch attempts
// (R2/R3) were likely sunk to their uses by the compiler (loads with
// register results can be). global_load_lds has NO destination register
// — it cannot be sunk. Each wave streams 8 rows through a private 4KB
// LDS slot: vmcnt(0) [stage had a full compute-phase to land: ~free] ->
// ds_read_b128 x4 -> lgkmcnt(0) -> issue DMA stage(r+1) -> compute+store
// row r. Next row's 4KB is in flight across the ENTIRE compute phase,
// by construction, with no registers held.
//
// Numerics: per-element math bit-identical to the verified kernel
// (absmax 4.27e-4 family):
//  - 1/sf, b, c, x0 via double-float Newton (rh+rl ~ 2^-46 rel).
//  - x/sf: double-float multiply + exact-residual FMA ~= CR f32 division.
//  - exp_int: pure f32 mul/add/ldexp/floor — bit-identical to numpy.
//  - Row sum: per-lane u32 over 16 elems < 2^30 (exact); lo16 chain
//    < 2^22, hi16 chain < 2^20 (exact u32); total < 2^36 exact in f64,
//    order-independent.
//  - factor: fac_exact == floor(2^32/sum) bit-exact.
//  - Epilogue reciprocals f32-rounded: rare +-1 A-quantum flips,
//    3.9e-4 << 1.87e-3 threshold.
//  - LDS race freedom: ds_reads are drained (lgkmcnt(0), asm fence)
//    before the next DMA into the same slot is issued; DMA data lands
//    ~900cy later. Slot is wave-private: no cross-wave hazard, no
//    barriers anywhere.
__global__ __launch_bounds__(TPB) void qsplit_int_softmax_kernel(
    const float* __restrict__ x,
    const float* __restrict__ scale_p,
    const float* __restrict__ thr_p,
    float* __restrict__ out,
    const int rows)
{
    const int tid  = threadIdx.x;
    const int lane = tid & 63;
    const int wid  = tid >> 6;

    __shared__ float lds[4][ROWLEN];    // 16 KB: one 4KB slot per wave

    const int gw = (int)(blockIdx.x << 2) | wid;       // 0..4095
    const int W  = (int)(gridDim.x << 2);              // 4096 row-streams
    const int chunk = (rows + W - 1) / W;              // 8
    int r          = gw * chunk;
    const int rend = (r + chunk < rows) ? (r + chunk) : rows;
    if (r >= rend) return;

    const float sf  = scale_p[0];   // 0.05f
    const float thr = thr_p[0];     // 0.1f

    // ---- f32 preamble: double-float 1/sf (SGPR-hoisted constants) ----
    const float rh = bcast_f32(1.0f / sf);                 // IEEE f32 div
    const float er = __builtin_fmaf(-sf, rh, 1.0f);        // residual
    const float rl = bcast_f32(rh * er);                   // rh+rl ~ 1/sf @2^-46

    // q = a/sf in double-float, then floor (margins: .137/.147/.845)
    #define DF_DIV(a) ({ float _p = (a) * rh; \
                         float _e = __builtin_fmaf((a), rh, -_p); \
                         _p + __builtin_fmaf((a), rl, _e); })
    const float x0f    = bcast_f32(floorf(DF_DIV(-0.69314718f)));    // -14
    const float bfc    = bcast_f32(floorf(DF_DIV(2.7073824f)));      // 54 (c1/c0)
    const float s2     = sf * sf;
    const float r2h    = 1.0f / s2;
    const float r2e    = __builtin_fmaf(-s2, r2h, 1.0f);
    const float r2l    = r2h * r2e;
    const float cq     = __builtin_fmaf(2.7921141f, r2l,
                         2.7921141f * r2h);                          // c2/c0/sf^2
    const float cfc    = bcast_f32(floorf(cq));                      // 1116
    const float clampf = bcast_f32(15.0f * x0f);                     // -210 exact
    const float invx0f = bcast_f32(1.0f / x0f);

    const float osA  = bcast_f32(thr / 255.0f);            // f32 div, as numpy
    const float osB  = bcast_f32(1.0f / 255.0f);
    const float invA = bcast_f32(1.0f / (4294967296.0f * osA)); // <=1ulp vs CR
    const float invB = bcast_f32(1.0f / (4294967296.0f * osB));
    const float thrq = bcast_f32(floorf(thr * 256.0f));    // 25

    // DMA one row into this wave's private LDS slot (no dest registers:
    // the compiler cannot sink these; 4KB in flight per call group).
    #define STAGE(row) do { \
        const float* _s = x + (size_t)(row) * ROWLEN + ((size_t)lane << 2); \
        _Pragma("unroll") \
        for (int _g = 0; _g < 4; ++_g) { \
            __builtin_amdgcn_global_load_lds( \
                (const __attribute__((address_space(1))) void*)(_s + (_g << 8)), \
                (__attribute__((address_space(3))) void*)&lds[wid][_g << 8], \
                16, 0, 0); \
        } \
    } while (0)

    // ---- prologue: stage first row ----
    STAGE(r);

    for (; r < rend; ++r) {
        // Stage for row r is complete (it had a full compute phase of
        // row r-1 to land; first iter pays the cold ~900cy once).
        // Also drains the previous iteration's 4 NT stores (old).
        asm volatile("s_waitcnt vmcnt(0)" ::: "memory");

        // ---- LDS -> registers (4x ds_read_b128) ----
        f32x4 w0 = *(const f32x4*)&lds[wid][(0 << 8) | (lane << 2)];
        f32x4 w1 = *(const f32x4*)&lds[wid][(1 << 8) | (lane << 2)];
        f32x4 w2 = *(const f32x4*)&lds[wid][(2 << 8) | (lane << 2)];
        f32x4 w3 = *(const f32x4*)&lds[wid][(3 << 8) | (lane << 2)];

        // Drain ds_reads before re-staging the same slot (race-proof,
        // ~120cy; DMA data would land ~900cy later anyway).
        asm volatile("s_waitcnt lgkmcnt(0)" ::: "memory");

        // ---- issue next row's DMA: in flight across this row's math ----
        if (r + 1 < rend) STAGE(r + 1);

        float a[16];
        a[0]=w0[0]; a[1]=w0[1]; a[2]=w0[2]; a[3]=w0[3];
        a[4]=w1[0]; a[5]=w1[1]; a[6]=w1[2]; a[7]=w1[3];
        a[8]=w2[0]; a[9]=w2[1]; a[10]=w2[2]; a[11]=w2[3];
        a[12]=w3[0]; a[13]=w3[1]; a[14]=w3[2]; a[15]=w3[3];

        // ---- x_int = x/sf via double-float (~CR f32 division) ----
        #pragma unroll
        for (int j = 0; j < 16; ++j) {
            const float xx = a[j];
            const float p  = xx * rh;
            const float e  = __builtin_fmaf(xx, rh, -p);   // exact residual
            a[j] = p + __builtin_fmaf(xx, rl, e);
        }

        // ---- row max: local tree (15 ops, depth 4) + one DPP chain ----
        float t0 = fmaxf(a[0],a[1]),  t1 = fmaxf(a[2],a[3]);
        float t2 = fmaxf(a[4],a[5]),  t3 = fmaxf(a[6],a[7]);
        float t4 = fmaxf(a[8],a[9]),  t5 = fmaxf(a[10],a[11]);
        float t6 = fmaxf(a[12],a[13]),t7 = fmaxf(a[14],a[15]);
        t0 = fmaxf(t0,t1); t2 = fmaxf(t2,t3); t4 = fmaxf(t4,t5); t6 = fmaxf(t6,t7);
        const float m = wave_max_dpp(fmaxf(fmaxf(t0,t2), fmaxf(t4,t6)));

        // ---- integer exp (f32/int, bit-matching numpy), in place ----
        unsigned usum = 0;    // <= 16 * 3.66e7 < 2^30: exact
        #pragma unroll
        for (int j = 0; j < 16; ++j) {
            float v = a[j] - m;                   // exact f32 sub
            v = fmaxf(v, clampf);                 // >= -210
            const float qf = floorf(v * invx0f);  // in [0,15]; flips benign
            const int   qi = (int)qf;
            const float rr = v - x0f * qf;        // exact in f32
            const float t  = rr + bfc;
            const float z  = rr * t + cfc;        // two roundings (contract off)
            float ei = floorf(ldexpf(z, 15 - qi)); // pow2 scale exact
            ei = fmaxf(ei, 0.0f);
            a[j] = ei;
            usum += (unsigned)ei;
        }

        // ---- row sum: lo/hi u32 DPP chains (exact, interleaved) ----
        unsigned lo = usum & 0xFFFFu, hi = usum >> 16;   // < 2^22 / < 2^20
        wave_sum_dpp2(lo, hi);
        const double s = (double)(((unsigned long long)hi << 16) + lo); // exact

        // ---- row-uniform epilogue constants ----
        const float fac_f = bcast_f32(fac_exact(s));                    // exact
        const float ath_f = bcast_f32((float)(((double)thrq * s) * (1.0 / 256.0)));

        // ---- quantize + nontemporal store ----
        float* po = out + (size_t)r * ROWLEN + ((size_t)lane << 2);
        #pragma unroll
        for (int g = 0; g < 4; ++g) {
            f32x4 o;
            #pragma unroll
            for (int jj = 0; jj < 4; ++jj) {
                const float ei  = a[4*g+jj];
                const bool  isA = (ei <= ath_f);
                const float t1_ = ei * fac_f;               // bit-matches numpy
                const float t2_ = t1_ * (isA ? invA : invB); // ~f32 division
                float si = floorf(t2_);
                si = fminf(si, isA ? 3.0e38f : 255.0f);     // cap only B path
                o[jj] = si * (isA ? osA : osB);
            }
            __builtin_nontemporal_store(o, (f32x4*)(po + (g << 8)));
        }
    }
    #undef STAGE
}

extern "C" void kernel_launch(void* const* d_in, const int* in_sizes, int n_in,
                              void* d_out, int out_size, void* d_ws, size_t ws_size,
                              hipStream_t stream) {
    const float* x     = (const float*)d_in[0];
    const float* scale = (const float*)d_in[1];
    const float* thr   = (const float*)d_in[2];
    float* out = (float*)d_out;

    const int total = in_sizes[0];        // 2*16*1024*1024
    const int rows  = total / ROWLEN;     // 32768 rows

    qsplit_int_softmax_kernel<<<dim3(BLOCKS), dim3(TPB), 0, stream>>>(
        x, scale, thr, out, rows);
}